// Round 2
// baseline (15144.130 us; speedup 1.0000x reference)
//
#include <hip/hip_runtime.h>
#include <hip/hip_cooperative_groups.h>
#include <math.h>

namespace cg = cooperative_groups;

// Problem constants
#define BB 256   // batch
#define TT 128   // seq len
#define DD 256   // input dim
#define HH 512   // hidden (LSTM fwd/bwd); layer-3 hidden = 1024

typedef __bf16 bf16x8 __attribute__((ext_vector_type(8)));
typedef float  f32x4  __attribute__((ext_vector_type(4)));

__device__ inline unsigned short f2bf(float f) {
  unsigned u = __builtin_bit_cast(unsigned, f);
  unsigned r = (u + 0x7fffu + ((u >> 16) & 1u)) >> 16;  // RNE
  return (unsigned short)r;
}
__device__ inline float sigm(float x)   { return 1.f / (1.f + __expf(-x)); }
__device__ inline float tanh_f(float x) { return 2.f / (1.f + __expf(-2.f * x)) - 1.f; }
__device__ inline bf16x8 ld8(const unsigned short* p) {
  return *reinterpret_cast<const bf16x8*>(p);
}

// ---------------------------------------------------------------------------
// Prep: convert/pack to bf16, gate-interleaved weights (row n = j*4+g),
// K = [ih | hh]. xb transposed to [T][B][D]. Zero comb slot 0 + hs slots.
// ---------------------------------------------------------------------------
__global__ void prep(const float* __restrict__ x,
                     const float* __restrict__ Wf_ih, const float* __restrict__ Wf_hh, const float* __restrict__ bf_,
                     const float* __restrict__ Wb_ih, const float* __restrict__ Wb_hh, const float* __restrict__ bb_,
                     const float* __restrict__ Ws_ih, const float* __restrict__ Ws_hh, const float* __restrict__ bs_,
                     unsigned short* __restrict__ xb, unsigned short* __restrict__ Wpf,
                     unsigned short* __restrict__ Wpb, unsigned short* __restrict__ Wps,
                     float* __restrict__ bpf, float* __restrict__ bpb, float* __restrict__ bps,
                     unsigned short* __restrict__ comb, unsigned short* __restrict__ hs) {
  const long gid = (long)blockIdx.x * blockDim.x + threadIdx.x;
  const long stride = (long)gridDim.x * blockDim.x;

  for (long i = gid; i < (long)BB * TT * DD; i += stride) {
    long k = i % DD;
    long bt = i / DD;
    long t = bt % TT;
    long b = bt / TT;
    xb[(t * BB + b) * DD + k] = f2bf(x[i]);
  }
  for (long i = gid; i < 2048L * 768; i += stride) {
    int n = (int)(i / 768), k = (int)(i - (long)n * 768);
    int j = n >> 2, g = n & 3;
    float vf = (k < DD) ? Wf_ih[(size_t)(g * HH + j) * DD + k]
                        : Wf_hh[(size_t)(g * HH + j) * HH + (k - DD)];
    float vb = (k < DD) ? Wb_ih[(size_t)(g * HH + j) * DD + k]
                        : Wb_hh[(size_t)(g * HH + j) * HH + (k - DD)];
    Wpf[i] = f2bf(vf);
    Wpb[i] = f2bf(vb);
  }
  for (long i = gid; i < 4096L * 2048; i += stride) {
    int n = (int)(i >> 11), k = (int)(i & 2047);
    int j = n >> 2, g = n & 3;
    float v = (k < 1024) ? Ws_ih[(size_t)(g * 1024 + j) * 1024 + k]
                         : Ws_hh[(size_t)(g * 1024 + j) * 1024 + (k - 1024)];
    Wps[i] = f2bf(v);
  }
  for (long i = gid; i < 2048; i += stride) {
    int j = (int)(i >> 2), g = (int)(i & 3);
    bpf[i] = bf_[g * HH + j];
    bpb[i] = bb_[g * HH + j];
  }
  for (long i = gid; i < 4096; i += stride) {
    int j = (int)(i >> 2), g = (int)(i & 3);
    bps[i] = bs_[g * 1024 + j];
  }
  for (long i = gid; i < (long)BB * 1024; i += stride) comb[i] = 0;
  for (long i = gid; i < 2L * BB * 1024; i += stride) hs[i] = 0;
}

// ---------------------------------------------------------------------------
// 64x64 tile GEMM, K = NPAIR*64, A split at element KS between aLo/aHi.
// Prefetch distance = 2 pairs (3 register buffer sets). Fully unrolled.
// ---------------------------------------------------------------------------
template <int NPAIR, int KS>
__device__ __forceinline__ void gemm_tile(
    const unsigned short* __restrict__ bp,
    const unsigned short* aLo0, const unsigned short* aLo1,
    const unsigned short* aLo2, const unsigned short* aLo3,
    const unsigned short* aHi0, const unsigned short* aHi1,
    const unsigned short* aHi2, const unsigned short* aHi3,
    f32x4 acc[4]) {
  const unsigned short* aLo[4] = {aLo0, aLo1, aLo2, aLo3};
  const unsigned short* aHi[4] = {aHi0, aHi1, aHi2, aHi3};

  bf16x8 bv[3][2];
  bf16x8 av[3][2][4];

#pragma unroll
  for (int p = 0; p < 2 && p < NPAIR; ++p) {
#pragma unroll
    for (int u = 0; u < 2; ++u) {
      const int kk = p * 64 + u * 32;
      bv[p][u] = ld8(bp + kk);
#pragma unroll
      for (int mb = 0; mb < 4; ++mb)
        av[p][u][mb] = (kk < KS) ? ld8(aLo[mb] + kk) : ld8(aHi[mb] + kk - KS);
    }
  }

#pragma unroll
  for (int p = 0; p < NPAIR; ++p) {
    const int cur = p % 3;
    if (p + 2 < NPAIR) {
      const int nxt = (p + 2) % 3;
#pragma unroll
      for (int u = 0; u < 2; ++u) {
        const int kk = (p + 2) * 64 + u * 32;
        bv[nxt][u] = ld8(bp + kk);
#pragma unroll
        for (int mb = 0; mb < 4; ++mb)
          av[nxt][u][mb] = (kk < KS) ? ld8(aLo[mb] + kk) : ld8(aHi[mb] + kk - KS);
      }
    }
#pragma unroll
    for (int u = 0; u < 2; ++u)
#pragma unroll
      for (int mb = 0; mb < 4; ++mb)
        acc[mb] = __builtin_amdgcn_mfma_f32_16x16x32_bf16(av[cur][u][mb], bv[cur][u], acc[mb], 0, 0, 0);
  }
}

// ---------------------------------------------------------------------------
// Persistent cooperative kernel.
// Blocks 0..255: fwd/bwd LSTM tiles (dir = bi>>7), step t = it.
// Blocks 256..511: layer-3 LSTM tiles, step t = it-1.
// grid.sync() between iterations. c state lives in registers per block.
// Classifier fused at the end (blocks 0..255, one batch row each).
// ---------------------------------------------------------------------------
__global__ __launch_bounds__(256, 2) void persistent(
    const unsigned short* __restrict__ xb,
    const unsigned short* __restrict__ Wpf, const unsigned short* __restrict__ Wpb,
    const unsigned short* __restrict__ Wps,
    const float* __restrict__ bpf, const float* __restrict__ bpb,
    const float* __restrict__ bps,
    unsigned short* __restrict__ comb, unsigned short* __restrict__ hs,
    const float* __restrict__ Wl, const float* __restrict__ blv,
    float* __restrict__ out) {
  cg::grid_group grid = cg::this_grid();
  __shared__ float lds[64 * 68];
  __shared__ float red[8];

  const int bi = blockIdx.x;
  const int tid = threadIdx.x;
  const int w = tid >> 6;
  const int lane = tid & 63;
  const int q = lane >> 4;
  const int ln = lane & 15;
  const int col = w * 16 + ln;

  float c_reg[4] = {0.f, 0.f, 0.f, 0.f};

  if (bi < 256) {
    // ---------------- fwd/bwd layer ----------------
    const int dir = bi >> 7;
    const int rr0 = bi & 127;
    const int m0 = (rr0 >> 5) * 64;
    const int n0 = (rr0 & 31) * 64;
    const unsigned short* __restrict__ W = dir ? Wpb : Wpf;
    const float* __restrict__ bias = dir ? bpb : bpf;
    const int dofs = dir ? HH : 0;
    const unsigned short* bp = W + (size_t)(n0 + col) * 768 + q * 8;
    const int jbase = n0 >> 2;

    for (int it = 0; it <= TT; ++it) {
      if (it < TT) {
        const int t = it;
        const int tx = dir ? (TT - 1 - t) : t;
        const unsigned short* aLo[4];
        const unsigned short* aHi[4];
#pragma unroll
        for (int mb = 0; mb < 4; ++mb) {
          const int brow = m0 + mb * 16 + ln;
          aLo[mb] = xb + ((size_t)tx * BB + brow) * DD + q * 8;
          aHi[mb] = comb + ((size_t)t * BB + brow) * 1024 + dofs + q * 8;
        }
        f32x4 acc[4];
#pragma unroll
        for (int mb = 0; mb < 4; ++mb) acc[mb] = (f32x4){0.f, 0.f, 0.f, 0.f};
        gemm_tile<12, 256>(bp, aLo[0], aLo[1], aLo[2], aLo[3],
                           aHi[0], aHi[1], aHi[2], aHi[3], acc);

#pragma unroll
        for (int mb = 0; mb < 4; ++mb)
#pragma unroll
          for (int r = 0; r < 4; ++r)
            lds[(mb * 16 + q * 4 + r) * 68 + col] = acc[mb][r];
        __syncthreads();

        unsigned short* hbase = comb + (size_t)(t + 1) * BB * 1024 + dofs;
#pragma unroll
        for (int r = 0; r < 4; ++r) {
          const int bl = tid & 63;
          const int jl = (tid >> 6) + r * 4;
          const float* gp = &lds[bl * 68 + jl * 4];
          const float* bp2 = bias + n0 + jl * 4;
          const float gi = gp[0] + bp2[0];
          const float gf = gp[1] + bp2[1];
          const float gg = gp[2] + bp2[2];
          const float go = gp[3] + bp2[3];
          const float c_new = sigm(gf) * c_reg[r] + sigm(gi) * tanh_f(gg);
          c_reg[r] = c_new;
          hbase[(size_t)(m0 + bl) * 1024 + jbase + jl] = f2bf(sigm(go) * tanh_f(c_new));
        }
      }
      grid.sync();
    }
  } else {
    // ---------------- layer-3 LSTM ----------------
    const int bi2 = bi - 256;
    const int m0 = (bi2 >> 6) * 64;
    const int n0 = (bi2 & 63) * 64;
    const unsigned short* bp = Wps + (size_t)(n0 + col) * 2048 + q * 8;
    const int jbase = n0 >> 2;

    for (int it = 0; it <= TT; ++it) {
      if (it >= 1) {
        const int t = it - 1;
        const unsigned short* aLo[4];
        const unsigned short* aHi[4];
#pragma unroll
        for (int mb = 0; mb < 4; ++mb) {
          const int brow = m0 + mb * 16 + ln;
          aLo[mb] = comb + ((size_t)(t + 1) * BB + brow) * 1024 + q * 8;
          aHi[mb] = hs + ((size_t)(t & 1) * BB + brow) * 1024 + q * 8;
        }
        f32x4 acc[4];
#pragma unroll
        for (int mb = 0; mb < 4; ++mb) acc[mb] = (f32x4){0.f, 0.f, 0.f, 0.f};
        gemm_tile<32, 1024>(bp, aLo[0], aLo[1], aLo[2], aLo[3],
                            aHi[0], aHi[1], aHi[2], aHi[3], acc);

#pragma unroll
        for (int mb = 0; mb < 4; ++mb)
#pragma unroll
          for (int r = 0; r < 4; ++r)
            lds[(mb * 16 + q * 4 + r) * 68 + col] = acc[mb][r];
        __syncthreads();

        unsigned short* hbase = hs + (size_t)((t + 1) & 1) * BB * 1024;
#pragma unroll
        for (int r = 0; r < 4; ++r) {
          const int bl = tid & 63;
          const int jl = (tid >> 6) + r * 4;
          const float* gp = &lds[bl * 68 + jl * 4];
          const float* bp2 = bps + n0 + jl * 4;
          const float gi = gp[0] + bp2[0];
          const float gf = gp[1] + bp2[1];
          const float gg = gp[2] + bp2[2];
          const float go = gp[3] + bp2[3];
          const float c_new = sigm(gf) * c_reg[r] + sigm(gi) * tanh_f(gg);
          c_reg[r] = c_new;
          hbase[(size_t)(m0 + bl) * 1024 + jbase + jl] = f2bf(sigm(go) * tanh_f(c_new));
        }
      }
      grid.sync();
    }
  }

  // ---------------- classifier (final h is hs slot 0; T even) -------------
  if (bi < 256) {
    const int b = bi;
    const unsigned short* hb = hs + (size_t)b * 1024;
    float s0 = 0.f, s1 = 0.f;
#pragma unroll
    for (int kk = 0; kk < 4; ++kk) {
      const int k = tid * 4 + kk;
      const float hv = __builtin_bit_cast(float, (unsigned)hb[k] << 16);
      s0 += hv * Wl[k];
      s1 += hv * Wl[1024 + k];
    }
    for (int off = 32; off > 0; off >>= 1) {
      s0 += __shfl_down(s0, off);
      s1 += __shfl_down(s1, off);
    }
    if ((tid & 63) == 0) { red[w * 2] = s0; red[w * 2 + 1] = s1; }
    __syncthreads();
    if (tid == 0) {
      const float l0 = red[0] + red[2] + red[4] + red[6] + blv[0];
      const float l1 = red[1] + red[3] + red[5] + red[7] + blv[1];
      out[b * 2 + 0] = sigm(l0);
      out[b * 2 + 1] = sigm(l1);
    }
  }
}

// ---------------------------------------------------------------------------
extern "C" void kernel_launch(void* const* d_in, const int* in_sizes, int n_in,
                              void* d_out, int out_size, void* d_ws, size_t ws_size,
                              hipStream_t stream) {
  const float* x     = (const float*)d_in[0];
  const float* Wf_ih = (const float*)d_in[1];
  const float* Wf_hh = (const float*)d_in[2];
  const float* bf_   = (const float*)d_in[3];
  const float* Wb_ih = (const float*)d_in[4];
  const float* Wb_hh = (const float*)d_in[5];
  const float* bb_   = (const float*)d_in[6];
  const float* Ws_ih = (const float*)d_in[7];
  const float* Ws_hh = (const float*)d_in[8];
  const float* bs_   = (const float*)d_in[9];
  const float* Wl    = (const float*)d_in[10];
  const float* bl_   = (const float*)d_in[11];
  float* out = (float*)d_out;

  char* ws = (char*)d_ws;
  size_t off = 0;
  auto take = [&](size_t bytes) -> void* {
    void* p = ws + off;
    off += (bytes + 255) & ~(size_t)255;
    return p;
  };
  unsigned short* xb   = (unsigned short*)take((size_t)BB * TT * DD * 2);
  unsigned short* Wpf  = (unsigned short*)take((size_t)2048 * 768 * 2);
  unsigned short* Wpb  = (unsigned short*)take((size_t)2048 * 768 * 2);
  unsigned short* Wps  = (unsigned short*)take((size_t)4096 * 2048 * 2);
  float* bpf = (float*)take(2048 * 4);
  float* bpb = (float*)take(2048 * 4);
  float* bps = (float*)take(4096 * 4);
  unsigned short* comb = (unsigned short*)take((size_t)(TT + 1) * BB * 1024 * 2);
  unsigned short* hs   = (unsigned short*)take((size_t)2 * BB * 1024 * 2);

  prep<<<2048, 256, 0, stream>>>(x, Wf_ih, Wf_hh, bf_, Wb_ih, Wb_hh, bb_,
                                 Ws_ih, Ws_hh, bs_, xb, Wpf, Wpb, Wps,
                                 bpf, bpb, bps, comb, hs);

  void* args[] = {(void*)&xb, (void*)&Wpf, (void*)&Wpb, (void*)&Wps,
                  (void*)&bpf, (void*)&bpb, (void*)&bps,
                  (void*)&comb, (void*)&hs,
                  (void*)&Wl, (void*)&bl_, (void*)&out};
  hipLaunchCooperativeKernel((const void*)persistent, dim3(512), dim3(256),
                             args, 0, stream);
}